// Round 3
// baseline (331.217 us; speedup 1.0000x reference)
//
#include <hip/hip_runtime.h>

#define ROWS    32
#define THREADS 1024
#define BINS    512
#define WORDS   (BINS/2)        // packed u16 counts: 256 u32 words per row
#define HSTRIDE (WORDS + 1)     // 257: row offset = 1 bank -> spreads atomic rows
#define LO      (-0.6f)
#define RANGE   (1.3f)

typedef short bf16x8 __attribute__((ext_vector_type(8)));
typedef float f32x4  __attribute__((ext_vector_type(4)));

// fp32 -> bf16 with round-to-nearest-even
__device__ __forceinline__ short f2bf(float f) {
    unsigned int u = __builtin_bit_cast(unsigned int, f);
    u = (u + 0x7FFFu + ((u >> 16) & 1u)) >> 16;
    return (short)u;
}

// pre-pass: fp32 X -> bf16 (one float4 per thread)
__global__ __launch_bounds__(256)
void cvt_kernel(const float* __restrict__ X, short* __restrict__ Xb) {
    int i = blockIdx.x * 256 + threadIdx.x;   // 0 .. 2097151
    float4 v = ((const float4*)X)[i];
    short4 s = { f2bf(v.x), f2bf(v.y), f2bf(v.z), f2bf(v.w) };
    ((short4*)Xb)[i] = s;
}

__global__ __launch_bounds__(THREADS, 4)
void scpp_kernel(const short* __restrict__ X, float* __restrict__ out) {
    const int t    = threadIdx.x;
    const int wave = t >> 6;
    const int lane = t & 63;
    const int q    = lane >> 4;   // quad 0..3
    const int ln   = lane & 15;
    const int bid  = blockIdx.x;       // 0..1023
    const int batch = bid >> 7;        // 128 wgs per batch
    const int m0    = (bid & 127) * ROWS;
    const short* Xb = X + (size_t)batch * 4096 * 256;

    __shared__ short        As[ROWS * 264];        // 32 rows x 256 bf16, stride 264
    __shared__ unsigned int hist[ROWS * HSTRIDE];  // 32 rows x 512 bins (u16-packed)

    // zero histograms (8224 words incl. pad)
    for (int i = t; i < ROWS * HSTRIDE; i += THREADS) hist[i] = 0u;

    // stage A tile (32 rows x 256) as bf16 into LDS (one 16B copy per thread)
    {
        int r  = t >> 5;               // 0..31
        int cs = (t & 31) * 8;         // 0..248
        *(bf16x8*)(&As[r * 264 + cs]) = *(const bf16x8*)(Xb + (size_t)(m0 + r) * 256 + cs);
    }
    __syncthreads();

    // hoist A fragments into registers: invariant across all 16 nt iterations
    bf16x8 af0[8], af1[8];
    #pragma unroll
    for (int ks = 0; ks < 8; ++ks) {
        af0[ks] = *(const bf16x8*)(&As[ln * 264 + q * 8 + ks * 32]);          // rows 0..15
        af1[ks] = *(const bf16x8*)(&As[(16 + ln) * 264 + q * 8 + ks * 32]);   // rows 16..31
    }

    // bin transform: b = (v/256 - LO) * BINS/RANGE  ==  v*scale + off
    const float scale = ((float)BINS / RANGE) / 256.0f;
    const float off   = -LO * ((float)BINS / RANGE);

    // main loop: 16 n-tiles of 256 cols; wave w owns cols nt*256 + 16w + ln
    for (int nt = 0; nt < 16; ++nt) {
        f32x4 acc0 = {0.f, 0.f, 0.f, 0.f};
        f32x4 acc1 = {0.f, 0.f, 0.f, 0.f};
        const int col = nt * 256 + wave * 16 + ln;
        const short* bp = Xb + (size_t)col * 256 + q * 8;
        #pragma unroll
        for (int ks = 0; ks < 8; ++ks) {               // K = 256 = 8 x 32
            bf16x8 bfr = *(const bf16x8*)(bp + ks * 32);
            acc0 = __builtin_amdgcn_mfma_f32_16x16x32_bf16(af0[ks], bfr, acc0, 0, 0, 0);
            acc1 = __builtin_amdgcn_mfma_f32_16x16x32_bf16(af1[ks], bfr, acc1, 0, 0, 0);
        }
        // D layout: lane holds D[4q+reg][ln]
        #pragma unroll
        for (int reg = 0; reg < 4; ++reg) {
            {
                int b = (int)(acc0[reg] * scale + off);
                b = b < 0 ? 0 : (b > BINS - 1 ? BINS - 1 : b);
                int row = 4 * q + reg;
                atomicAdd(&hist[row * HSTRIDE + (b >> 1)], 1u << ((b & 1) * 16));
            }
            {
                int b = (int)(acc1[reg] * scale + off);
                b = b < 0 ? 0 : (b > BINS - 1 ? BINS - 1 : b);
                int row = 16 + 4 * q + reg;
                atomicAdd(&hist[row * HSTRIDE + (b >> 1)], 1u << ((b & 1) * 16));
            }
        }
    }
    __syncthreads();

    // descending suffix-sum per row, in place (wave handles rows 2w, 2w+1)
    #pragma unroll
    for (int rr = 0; rr < 2; ++rr) {
        int r = wave * 2 + rr;
        unsigned int* H = &hist[r * HSTRIDE];
        unsigned int wd[4];
        int c[8];
        #pragma unroll
        for (int i2 = 0; i2 < 4; ++i2) wd[i2] = H[4 * lane + i2];
        #pragma unroll
        for (int i2 = 0; i2 < 4; ++i2) {
            c[2 * i2]     = (int)(wd[i2] & 0xFFFFu);
            c[2 * i2 + 1] = (int)(wd[i2] >> 16);
        }
        int local = 0;
        #pragma unroll
        for (int u = 0; u < 8; ++u) local += c[u];
        int suf = local;
        #pragma unroll
        for (int off2 = 1; off2 < 64; off2 <<= 1) {
            int o = __shfl_down(suf, off2, 64);
            if (lane + off2 < 64) suf += o;
        }
        int run = suf - local;  // sum over higher lanes (higher bins)
        int s[8];
        #pragma unroll
        for (int u = 7; u >= 0; --u) { run += c[u]; s[u] = run; }
        #pragma unroll
        for (int i2 = 0; i2 < 4; ++i2)
            H[4 * lane + i2] = (unsigned int)s[2 * i2] | ((unsigned int)s[2 * i2 + 1] << 16);
    }
    __syncthreads();

    // rank extraction: S[j] = #values >= bin-j lower edge; find max j with S[j] >= k
    const float binw = RANGE / (float)BINS;
    #pragma unroll
    for (int rep = 0; rep < 8; ++rep) {
        int o = rep * THREADS + t;     // 0..8191
        int r = o >> 8;                // local row 0..31
        int i = o & 255;               // pool index
        float rv = 1.0f + (float)i * (4094.0f / 255.0f);
        int k = (int)rintf(rv) + 1;    // k-th largest, k in [2, 4096]
        const unsigned int* H = &hist[r * HSTRIDE];
        int j = 0;
        #pragma unroll
        for (int step = 256; step >= 1; step >>= 1) {
            int cand = j + step;
            if (cand < BINS) {
                unsigned int wv = H[cand >> 1];
                int S = (cand & 1) ? (int)(wv >> 16) : (int)(wv & 0xFFFFu);
                if (S >= k) j = cand;
            }
        }
        out[(size_t)(batch * 4096 + m0 + r) * 256 + i] = LO + ((float)j + 0.5f) * binw;
    }
}

extern "C" void kernel_launch(void* const* d_in, const int* in_sizes, int n_in,
                              void* d_out, int out_size, void* d_ws, size_t ws_size,
                              hipStream_t stream) {
    const float* x = (const float*)d_in[0];
    float* out = (float*)d_out;
    const size_t nelem = (size_t)8 * 4096 * 256;          // 8,388,608
    short* xb = (short*)d_ws;
    hipLaunchKernelGGL(cvt_kernel, dim3(nelem / 1024), dim3(256), 0, stream, x, xb);
    hipLaunchKernelGGL(scpp_kernel, dim3(1024), dim3(THREADS), 0, stream, xb, out);
}

// Round 4
// 324.129 us; speedup vs baseline: 1.0219x; 1.0219x over previous
//
#include <hip/hip_runtime.h>

#define ROWS    32
#define THREADS 512            // 8 waves -> 4 blocks/CU (wave-limited), 100% occupancy
#define BINS    512
#define HWORDS  128            // byte-packed: 4 bins per u32 word, bank-aligned rows
#define LO      (-0.6f)
#define RANGE   (1.3f)

typedef short bf16x8 __attribute__((ext_vector_type(8)));
typedef float f32x4  __attribute__((ext_vector_type(4)));

// fp32 -> bf16 with round-to-nearest-even
__device__ __forceinline__ short f2bf(float f) {
    unsigned int u = __builtin_bit_cast(unsigned int, f);
    u = (u + 0x7FFFu + ((u >> 16) & 1u)) >> 16;
    return (short)u;
}

// pre-pass: fp32 X -> bf16 (one float4 per thread)
__global__ __launch_bounds__(256)
void cvt_kernel(const float* __restrict__ X, short* __restrict__ Xb) {
    int i = blockIdx.x * 256 + threadIdx.x;   // 0 .. 2097151
    float4 v = ((const float4*)X)[i];
    short4 s = { f2bf(v.x), f2bf(v.y), f2bf(v.z), f2bf(v.w) };
    ((short4*)Xb)[i] = s;
}

__global__ __launch_bounds__(THREADS)
void scpp_kernel(const short* __restrict__ X, float* __restrict__ out) {
    const int t    = threadIdx.x;
    const int wave = t >> 6;           // 0..7
    const int lane = t & 63;
    const int q    = lane >> 4;        // quad 0..3
    const int ln   = lane & 15;
    const int bid  = blockIdx.x;       // 0..1023
    const int batch = bid >> 7;        // 128 wgs per batch
    const int m0    = (bid & 127) * ROWS;
    const short* Xb = X + (size_t)batch * 4096 * 256;

    __shared__ short        As[ROWS * 264];       // 32 rows x 256 bf16, stride 264
    __shared__ unsigned int hist[ROWS * HWORDS];  // 32 rows x 512 bins, u8-packed

    // zero histograms: 4096 words
    #pragma unroll
    for (int i = 0; i < (ROWS * HWORDS) / THREADS; ++i)
        hist[t + THREADS * i] = 0u;

    // stage A tile (32 rows x 256) as bf16 into LDS: 1024 bf16x8 tasks
    #pragma unroll
    for (int i = 0; i < 2; ++i) {
        int id = t + THREADS * i;      // 0..1023
        int r  = id >> 5;              // 0..31
        int cs = (id & 31) * 8;        // 0..248
        *(bf16x8*)(&As[r * 264 + cs]) = *(const bf16x8*)(Xb + (size_t)(m0 + r) * 256 + cs);
    }
    __syncthreads();

    // bin transform: b = (v/256 - LO) * BINS/RANGE == v*scale + off
    const float scale = ((float)BINS / RANGE) / 256.0f;
    const float off   = -LO * ((float)BINS / RANGE);

    // main loop: 32 n-tiles of 128 cols; wave w owns cols nt*128 + 16w + ln
    for (int nt = 0; nt < 32; ++nt) {
        f32x4 acc0 = {0.f, 0.f, 0.f, 0.f};
        f32x4 acc1 = {0.f, 0.f, 0.f, 0.f};
        const int col = nt * 128 + wave * 16 + ln;
        const short* bp  = Xb + (size_t)col * 256 + q * 8;
        const short* ap0 = &As[ln * 264 + q * 8];          // rows 0..15
        const short* ap1 = &As[(16 + ln) * 264 + q * 8];   // rows 16..31
        #pragma unroll
        for (int ks = 0; ks < 8; ++ks) {                   // K = 256 = 8 x 32
            bf16x8 bfr = *(const bf16x8*)(bp + ks * 32);
            bf16x8 af0 = *(const bf16x8*)(ap0 + ks * 32);
            bf16x8 af1 = *(const bf16x8*)(ap1 + ks * 32);
            acc0 = __builtin_amdgcn_mfma_f32_16x16x32_bf16(af0, bfr, acc0, 0, 0, 0);
            acc1 = __builtin_amdgcn_mfma_f32_16x16x32_bf16(af1, bfr, acc1, 0, 0, 0);
        }
        // D layout: lane holds D[4q+reg][ln]
        #pragma unroll
        for (int reg = 0; reg < 4; ++reg) {
            {
                int b = (int)(acc0[reg] * scale + off);
                b = b < 0 ? 0 : (b > BINS - 1 ? BINS - 1 : b);
                int row = 4 * q + reg;
                atomicAdd(&hist[row * HWORDS + (b >> 2)], 1u << ((b & 3) * 8));
            }
            {
                int b = (int)(acc1[reg] * scale + off);
                b = b < 0 ? 0 : (b > BINS - 1 ? BINS - 1 : b);
                int row = 16 + 4 * q + reg;
                atomicAdd(&hist[row * HWORDS + (b >> 2)], 1u << ((b & 3) * 8));
            }
        }
    }
    __syncthreads();

    // epilogue, fully in-register per wave: rows 4w .. 4w+3
    const float binw = RANGE / (float)BINS;
    #pragma unroll
    for (int rr = 0; rr < 4; ++rr) {
        const int r = wave * 4 + rr;
        const unsigned int* H = &hist[r * HWORDS];
        // lane L holds bins 8L..8L+7 (2 words, 8 bytes)
        unsigned int w0 = H[2 * lane];
        unsigned int w1 = H[2 * lane + 1];
        int c[8] = { (int)(w0 & 255u), (int)((w0 >> 8) & 255u),
                     (int)((w0 >> 16) & 255u), (int)(w0 >> 24),
                     (int)(w1 & 255u), (int)((w1 >> 8) & 255u),
                     (int)((w1 >> 16) & 255u), (int)(w1 >> 24) };
        int local = 0;
        #pragma unroll
        for (int u = 0; u < 8; ++u) local += c[u];
        // suffix-sum over lanes (sum of locals at lanes > this one, + own)
        int suf = local;
        #pragma unroll
        for (int o2 = 1; o2 < 64; o2 <<= 1) {
            int o = __shfl_down(suf, o2, 64);
            if (lane + o2 < 64) suf += o;
        }
        int run = suf - local;
        int s[8];                         // s[u] = S[8*lane + u] = #values >= bin edge
        #pragma unroll
        for (int u = 7; u >= 0; --u) { run += c[u]; s[u] = run; }

        // answer 256 queries for this row: lane handles i = qq*64 + lane
        #pragma unroll
        for (int qq = 0; qq < 4; ++qq) {
            int i = qq * 64 + lane;
            float rv = 1.0f + (float)i * (4094.0f / 255.0f);
            int k = (int)rintf(rv) + 1;   // k-th largest, k in [2, 4096]
            // binary search over lanes for last L with S[8L] >= k  (S[0]=4096>=k)
            int Lo = 0;
            #pragma unroll
            for (int st = 32; st >= 1; st >>= 1) {
                int cand = Lo + st;       // always <= 63
                int v = __shfl(s[0], cand, 64);
                if (v >= k) Lo = cand;
            }
            // within lane Lo's 8 bins: j_off = #{u: S[8Lo+u] >= k} - 1
            int j8 = 0;
            #pragma unroll
            for (int u = 0; u < 8; ++u) {
                int v = __shfl(s[u], Lo, 64);
                j8 += (v >= k) ? 1 : 0;
            }
            int j = 8 * Lo + j8 - 1;
            out[(size_t)(batch * 4096 + m0 + r) * 256 + i] = LO + ((float)j + 0.5f) * binw;
        }
    }
}

extern "C" void kernel_launch(void* const* d_in, const int* in_sizes, int n_in,
                              void* d_out, int out_size, void* d_ws, size_t ws_size,
                              hipStream_t stream) {
    const float* x = (const float*)d_in[0];
    float* out = (float*)d_out;
    const size_t nelem = (size_t)8 * 4096 * 256;          // 8,388,608
    short* xb = (short*)d_ws;
    hipLaunchKernelGGL(cvt_kernel, dim3(nelem / 1024), dim3(256), 0, stream, x, xb);
    hipLaunchKernelGGL(scpp_kernel, dim3(1024), dim3(THREADS), 0, stream, xb, out);
}